// Round 5
// baseline (1107.030 us; speedup 1.0000x reference)
//
#include <hip/hip_runtime.h>
#include <cstdint>
#include <cstddef>

#define NN 50000
#define EE 800000
#define EPQ (EE + NN)
#define NEG_SLOPE 0.2f
#define BN_EPS 1e-5f
#define SCB 256
#define NBLK ((NN + SCB - 1) / SCB)

typedef _Float16 f16x8 __attribute__((ext_vector_type(8)));
typedef _Float16 f16x4 __attribute__((ext_vector_type(4)));
typedef _Float16 f16x2 __attribute__((ext_vector_type(2)));
typedef float f32x4 __attribute__((ext_vector_type(4)));
typedef unsigned int u32;

static __device__ __forceinline__ float lrelu(float x) { return x > 0.f ? x : x * NEG_SLOPE; }

// async global->LDS, 16B per lane; LDS dest = wave-uniform base + lane*16
static __device__ __forceinline__ void gld_lds16(const void* g, void* l) {
    __builtin_amdgcn_global_load_lds((const __attribute__((address_space(1))) u32*)g,
                                     (__attribute__((address_space(3))) u32*)l, 16, 0, 0);
}

// ---------------- CSR build ----------------
__global__ void init_count(int* __restrict__ count) {
    int i = blockIdx.x * blockDim.x + threadIdx.x;
    if (i < NN) count[i] = 1;  // self loop
}

__global__ void hist_kernel(const int* __restrict__ dst, int* __restrict__ count) {
    int e = blockIdx.x * blockDim.x + threadIdx.x;
    if (e < EE) atomicAdd(&count[dst[e]], 1);
}

__global__ __launch_bounds__(SCB) void scan1(const int* __restrict__ count,
                                             int* __restrict__ excl, int* __restrict__ bsum) {
    __shared__ int tmp[SCB];
    int b = blockIdx.x, t = threadIdx.x;
    int i = b * SCB + t;
    int v = (i < NN) ? count[i] : 0;
    tmp[t] = v;
    __syncthreads();
    for (int off = 1; off < SCB; off <<= 1) {
        int u = (t >= off) ? tmp[t - off] : 0;
        __syncthreads();
        tmp[t] += u;
        __syncthreads();
    }
    if (i < NN) excl[i] = tmp[t] - v;
    if (t == SCB - 1) bsum[b] = tmp[t];
}

__global__ __launch_bounds__(256) void scan2(const int* __restrict__ bsum, int* __restrict__ boff) {
    __shared__ int tmp[256];
    int t = threadIdx.x;
    int v = (t < NBLK) ? bsum[t] : 0;
    tmp[t] = v;
    __syncthreads();
    for (int off = 1; off < 256; off <<= 1) {
        int u = (t >= off) ? tmp[t - off] : 0;
        __syncthreads();
        tmp[t] += u;
        __syncthreads();
    }
    boff[t] = tmp[t] - v;
}

__global__ void scan3(const int* __restrict__ excl, const int* __restrict__ boff,
                      int* __restrict__ rowptr, int* __restrict__ cursor) {
    int i = blockIdx.x * blockDim.x + threadIdx.x;
    if (i < NN) {
        int r = excl[i] + boff[i / SCB];
        rowptr[i] = r;
        cursor[i] = r;
    }
    if (i == NN) rowptr[NN] = EPQ;
}

__global__ void scatter_kernel(const int* __restrict__ src, const int* __restrict__ dst,
                               int* __restrict__ cursor, int* __restrict__ csrs) {
    int e = blockIdx.x * blockDim.x + threadIdx.x;
    if (e < EE) {
        int d = dst[e];
        int slot = atomicAdd(&cursor[d], 1);
        csrs[slot] = src[e];
    } else if (e < EPQ) {
        int i = e - EE;
        int slot = atomicAdd(&cursor[i], 1);
        csrs[slot] = i;
    }
}

// ---------------- casts ----------------
__global__ void cast_x_kernel(const float* __restrict__ in, _Float16* __restrict__ out, int n4) {
    int i = blockIdx.x * blockDim.x + threadIdx.x;
    if (i >= n4) return;
    f32x4 v = *(const f32x4*)(in + (size_t)i * 4);
    f16x4 o;
    o[0] = (_Float16)v[0]; o[1] = (_Float16)v[1]; o[2] = (_Float16)v[2]; o[3] = (_Float16)v[3];
    *(f16x4*)(out + (size_t)i * 4) = o;
}

// W [K][Nc] f32 -> Wt [Nc][K] f16
__global__ __launch_bounds__(256) void tcast_kernel(const float* __restrict__ W,
                                                    _Float16* __restrict__ Wt, int K, int Nc) {
    __shared__ float tile[32][33];
    int bx = blockIdx.x * 32;
    int by = blockIdx.y * 32;
    int tx = threadIdx.x & 31, ty = threadIdx.x >> 5;
#pragma unroll
    for (int r = 0; r < 32; r += 8) {
        int k = by + ty + r, n = bx + tx;
        tile[ty + r][tx] = (k < K && n < Nc) ? W[(size_t)k * Nc + n] : 0.f;
    }
    __syncthreads();
#pragma unroll
    for (int r = 0; r < 32; r += 8) {
        int n = bx + ty + r, k = by + tx;
        if (n < Nc && k < K) Wt[(size_t)n * K + k] = (_Float16)tile[tx][ty + r];
    }
}

// ---------------- f16 MFMA GEMM, double-buffered 2-phase prefetch ----------------
__global__ __launch_bounds__(256) void gemm_f16(const _Float16* __restrict__ A,
                                                const _Float16* __restrict__ Bt,
                                                _Float16* __restrict__ C, int M, int Nc, int K,
                                                int ldc) {
    __shared__ __align__(16) _Float16 As[2][128 * 64];
    __shared__ __align__(16) _Float16 Bs[2][128 * 64];
    const int t = threadIdx.x;
    const int bm = blockIdx.x * 128;
    const int bn = blockIdx.y * 128;
    const int wid = t >> 6, lane = t & 63;
    const int wm = (wid >> 1) * 64, wn = (wid & 1) * 64;
    f32x4 acc[4][4] = {};
    const int nsteps = K >> 6;

    auto STAGE = [&](int buf, int k0) {
#pragma unroll
        for (int it = 0; it < 4; ++it) {
            int rbase = it * 32 + wid * 8;        // wave-uniform
            int row = rbase + (lane >> 3);
            int c8g = (lane & 7) ^ (row & 7);     // pre-swizzled source chunk
            gld_lds16(A + (size_t)(bm + row) * K + k0 + c8g * 8, (char*)As[buf] + rbase * 128);
            gld_lds16(Bt + (size_t)(bn + row) * K + k0 + c8g * 8, (char*)Bs[buf] + rbase * 128);
        }
    };

    STAGE(0, 0);
    __syncthreads();
    int cur = 0;
    for (int s = 0; s < nsteps; ++s) {
        if (s + 1 < nsteps) STAGE(cur ^ 1, (s + 1) * 64);
#pragma unroll
        for (int ks = 0; ks < 2; ++ks) {
            f16x8 af[4], bf[4];
#pragma unroll
            for (int mi = 0; mi < 4; ++mi) {
                int row = wm + mi * 16 + (lane & 15);
                int c8 = (ks * 4 + (lane >> 4)) ^ (row & 7);
                af[mi] = *(const f16x8*)((const char*)As[cur] + row * 128 + c8 * 16);
            }
#pragma unroll
            for (int ni = 0; ni < 4; ++ni) {
                int row = wn + ni * 16 + (lane & 15);
                int c8 = (ks * 4 + (lane >> 4)) ^ (row & 7);
                bf[ni] = *(const f16x8*)((const char*)Bs[cur] + row * 128 + c8 * 16);
            }
#pragma unroll
            for (int mi = 0; mi < 4; ++mi)
#pragma unroll
                for (int ni = 0; ni < 4; ++ni)
                    acc[mi][ni] = __builtin_amdgcn_mfma_f32_16x16x32_f16(af[mi], bf[ni],
                                                                         acc[mi][ni], 0, 0, 0);
        }
        __syncthreads();
        cur ^= 1;
    }
#pragma unroll
    for (int mi = 0; mi < 4; ++mi) {
#pragma unroll
        for (int r = 0; r < 4; ++r) {
            int grow = bm + wm + mi * 16 + (lane >> 4) * 4 + r;
            if (grow < M) {
#pragma unroll
                for (int ni = 0; ni < 4; ++ni) {
                    int gcol = bn + wn + ni * 16 + (lane & 15);
                    if (gcol < Nc) C[(size_t)grow * ldc + gcol] = (_Float16)acc[mi][ni][r];
                }
            }
        }
    }
}

// ---------------- alpha (layers 0/1): one wave per node ----------------
__global__ __launch_bounds__(256) void alpha01(const _Float16* __restrict__ h,
                                               const float* __restrict__ aws,
                                               const float* __restrict__ awd,
                                               float* __restrict__ asn, float* __restrict__ adn) {
    int wid = threadIdx.x >> 6, lane = threadIdx.x & 63;
    int i = blockIdx.x * 4 + wid;
    if (i >= NN) return;
    f16x8 v = *(const f16x8*)(h + (size_t)i * 512 + lane * 8);
    float s = 0.f, d = 0.f;
#pragma unroll
    for (int j = 0; j < 8; j++) {
        float f = (float)v[j];
        s += f * aws[lane * 8 + j];
        d += f * awd[lane * 8 + j];
    }
#pragma unroll
    for (int off = 1; off < 16; off <<= 1) {
        s += __shfl_xor(s, off);
        d += __shfl_xor(d, off);
    }
    if ((lane & 15) == 0) {
        int hh = lane >> 4;
        asn[i * 4 + hh] = s;
        adn[i * 4 + hh] = d;
    }
}

// ---------------- per-edge normalized weights (layers 0/1): wave per node ----------------
__global__ __launch_bounds__(256) void wsoft01(const float* __restrict__ asn,
                                               const float* __restrict__ adn,
                                               const int* __restrict__ rowptr,
                                               const int* __restrict__ csr,
                                               _Float16* __restrict__ wA) {
    int wid = threadIdx.x >> 6, lane = threadIdx.x & 63;
    int i = blockIdx.x * 4 + wid;
    if (i >= NN) return;
    int start = rowptr[i], end = rowptr[i + 1], deg = end - start;
    f32x4 ad = *(const f32x4*)(adn + (size_t)i * 4);
    if (deg <= 64) {
        bool v = lane < deg;
        int e = start + (v ? lane : 0);
        int s = csr[e];
        f32x4 a = *(const f32x4*)(asn + (size_t)s * 4);
        f32x4 sc;
#pragma unroll
        for (int j = 0; j < 4; j++) sc[j] = v ? lrelu(a[j] + ad[j]) : -1e30f;
        f32x4 m = sc;
#pragma unroll
        for (int off = 32; off; off >>= 1)
#pragma unroll
            for (int j = 0; j < 4; j++) m[j] = fmaxf(m[j], __shfl_xor(m[j], off));
        f32x4 wv;
#pragma unroll
        for (int j = 0; j < 4; j++) wv[j] = v ? __expf(sc[j] - m[j]) : 0.f;
        f32x4 den = wv;
#pragma unroll
        for (int off = 32; off; off >>= 1)
#pragma unroll
            for (int j = 0; j < 4; j++) den[j] += __shfl_xor(den[j], off);
        if (v) {
            f16x4 o;
#pragma unroll
            for (int j = 0; j < 4; j++) o[j] = (_Float16)(wv[j] / (den[j] + 1e-16f));
            *(f16x4*)(wA + (size_t)e * 4) = o;
        }
    } else {
        f32x4 m = {-1e30f, -1e30f, -1e30f, -1e30f};
        for (int e = start + lane; e < end; e += 64) {
            int s = csr[e];
            f32x4 a = *(const f32x4*)(asn + (size_t)s * 4);
#pragma unroll
            for (int j = 0; j < 4; j++) m[j] = fmaxf(m[j], lrelu(a[j] + ad[j]));
        }
#pragma unroll
        for (int off = 32; off; off >>= 1)
#pragma unroll
            for (int j = 0; j < 4; j++) m[j] = fmaxf(m[j], __shfl_xor(m[j], off));
        f32x4 den = {0.f, 0.f, 0.f, 0.f};
        for (int e = start + lane; e < end; e += 64) {
            int s = csr[e];
            f32x4 a = *(const f32x4*)(asn + (size_t)s * 4);
#pragma unroll
            for (int j = 0; j < 4; j++) den[j] += __expf(lrelu(a[j] + ad[j]) - m[j]);
        }
#pragma unroll
        for (int off = 32; off; off >>= 1)
#pragma unroll
            for (int j = 0; j < 4; j++) den[j] += __shfl_xor(den[j], off);
        for (int e = start + lane; e < end; e += 64) {
            int s = csr[e];
            f32x4 a = *(const f32x4*)(asn + (size_t)s * 4);
            f16x4 o;
#pragma unroll
            for (int j = 0; j < 4; j++)
                o[j] = (_Float16)(__expf(lrelu(a[j] + ad[j]) - m[j]) / (den[j] + 1e-16f));
            *(f16x4*)(wA + (size_t)e * 4) = o;
        }
    }
}

// ---------------- sliced aggregation + bias + BN + ELU (layers 0/1) ----------------
// grid: 8 slices x ceil(NN/4); slice = bid%8 -> XCD affinity; 32-ch sub-passes
// keep each XCD's h working set at 3.2MB (fits 4MB L2).
__global__ __launch_bounds__(256) void agg01s(const _Float16* __restrict__ h,
                                              const _Float16* __restrict__ wA,
                                              const int* __restrict__ rowptr,
                                              const int* __restrict__ csr,
                                              const float* __restrict__ bias,
                                              const float* __restrict__ g,
                                              const float* __restrict__ bt,
                                              const float* __restrict__ mean,
                                              const float* __restrict__ var,
                                              _Float16* __restrict__ out) {
    int bid = blockIdx.x;
    int slice = bid & 7, grp = bid >> 3;
    int wid = threadIdx.x >> 6, lane = threadIdx.x & 63;
    int i = grp * 4 + wid;
    if (i >= NN) return;
    int start = rowptr[i], end = rowptr[i + 1];
    int lq = lane & 7, eq = lane >> 3;
    int head = slice >> 1;  // ch in [slice*64, slice*64+64) -> head wave-uniform
#pragma unroll
    for (int sub = 0; sub < 2; ++sub) {
        int ch = slice * 64 + sub * 32 + lq * 4;
        const char* hb = (const char*)h + (size_t)ch * 2;
        f32x4 acc = {0.f, 0.f, 0.f, 0.f}, acc2 = {0.f, 0.f, 0.f, 0.f};
        int e0 = start;
        for (; e0 + 16 <= end; e0 += 16) {
            int e = e0 + eq, e2 = e0 + 8 + eq;
            int s = csr[e], s2 = csr[e2];
            float w = (float)wA[(size_t)e * 4 + head];
            float w2 = (float)wA[(size_t)e2 * 4 + head];
            f16x4 p = *(const f16x4*)(hb + (u32)s * 1024u);
            f16x4 p2 = *(const f16x4*)(hb + (u32)s2 * 1024u);
#pragma unroll
            for (int j = 0; j < 4; j++) {
                acc[j] += w * (float)p[j];
                acc2[j] += w2 * (float)p2[j];
            }
        }
        for (; e0 < end; e0 += 8) {
            int e = e0 + eq;
            if (e < end) {
                int s = csr[e];
                float w = (float)wA[(size_t)e * 4 + head];
                f16x4 p = *(const f16x4*)(hb + (u32)s * 1024u);
#pragma unroll
                for (int j = 0; j < 4; j++) acc[j] += w * (float)p[j];
            }
        }
#pragma unroll
        for (int j = 0; j < 4; j++) acc[j] += acc2[j];
#pragma unroll
        for (int off = 8; off < 64; off <<= 1)
#pragma unroll
            for (int j = 0; j < 4; j++) acc[j] += __shfl_xor(acc[j], off);
        if (lane < 8) {
            f32x4 bi = *(const f32x4*)(bias + ch);
            f32x4 gg = *(const f32x4*)(g + ch);
            f32x4 bb = *(const f32x4*)(bt + ch);
            f32x4 mm = *(const f32x4*)(mean + ch);
            f32x4 vv = *(const f32x4*)(var + ch);
            f16x4 o;
#pragma unroll
            for (int j = 0; j < 4; j++) {
                float val = acc[j] + bi[j];
                val = (val - mm[j]) * (gg[j] * rsqrtf(vv[j] + BN_EPS)) + bb[j];
                val = val > 0.f ? val : expm1f(val);
                o[j] = (_Float16)val;
            }
            *(f16x4*)(out + (size_t)i * 512 + ch) = o;
        }
    }
}

// ---------------- layer 2: alpha (h2 padded stride 256) ----------------
__global__ __launch_bounds__(256) void alpha2k(const _Float16* __restrict__ h2,
                                               const float* __restrict__ aws,
                                               const float* __restrict__ awd,
                                               float* __restrict__ asn, float* __restrict__ adn) {
    int wid = threadIdx.x >> 6, lane = threadIdx.x & 63;
    int i = blockIdx.x * 4 + wid;
    if (i >= NN) return;
    const _Float16* row = h2 + (size_t)i * 256;
#pragma unroll
    for (int hh = 0; hh < 6; hh++) {
        float s = 0.f, d = 0.f;
        if (lane < 40) {
            float f = (float)row[hh * 40 + lane];
            s = f * aws[hh * 40 + lane];
            d = f * awd[hh * 40 + lane];
        }
#pragma unroll
        for (int off = 32; off; off >>= 1) {
            s += __shfl_xor(s, off);
            d += __shfl_xor(d, off);
        }
        if (lane == 0) {
            asn[(size_t)i * 8 + hh] = s;
            adn[(size_t)i * 8 + hh] = d;
        }
    }
}

// ---------------- layer-2 normalized weights (6 heads, stride-8 f16) ----------------
__global__ __launch_bounds__(256) void wsoft2(const float* __restrict__ asn,
                                              const float* __restrict__ adn,
                                              const int* __restrict__ rowptr,
                                              const int* __restrict__ csr,
                                              _Float16* __restrict__ w2) {
    int wid = threadIdx.x >> 6, lane = threadIdx.x & 63;
    int i = blockIdx.x * 4 + wid;
    if (i >= NN) return;
    int start = rowptr[i], end = rowptr[i + 1], deg = end - start;
    f32x4 ad0 = *(const f32x4*)(adn + (size_t)i * 8);
    f32x4 ad1 = *(const f32x4*)(adn + (size_t)i * 8 + 4);
    float adh[6] = {ad0[0], ad0[1], ad0[2], ad0[3], ad1[0], ad1[1]};
    if (deg <= 64) {
        bool v = lane < deg;
        int e = start + (v ? lane : 0);
        int s = csr[e];
        f32x4 x0 = *(const f32x4*)(asn + (size_t)s * 8);
        f32x4 x1 = *(const f32x4*)(asn + (size_t)s * 8 + 4);
        float av[6] = {x0[0], x0[1], x0[2], x0[3], x1[0], x1[1]};
        float sc[6], m[6], wv[6], den[6];
#pragma unroll
        for (int j = 0; j < 6; j++) {
            sc[j] = v ? lrelu(av[j] + adh[j]) : -1e30f;
            m[j] = sc[j];
        }
#pragma unroll
        for (int off = 32; off; off >>= 1)
#pragma unroll
            for (int j = 0; j < 6; j++) m[j] = fmaxf(m[j], __shfl_xor(m[j], off));
#pragma unroll
        for (int j = 0; j < 6; j++) {
            wv[j] = v ? __expf(sc[j] - m[j]) : 0.f;
            den[j] = wv[j];
        }
#pragma unroll
        for (int off = 32; off; off >>= 1)
#pragma unroll
            for (int j = 0; j < 6; j++) den[j] += __shfl_xor(den[j], off);
        if (v) {
            f16x8 o;
#pragma unroll
            for (int j = 0; j < 6; j++) o[j] = (_Float16)(wv[j] / (den[j] + 1e-16f));
            o[6] = (_Float16)0.f;
            o[7] = (_Float16)0.f;
            *(f16x8*)(w2 + (size_t)e * 8) = o;
        }
    } else {
        float m[6], den[6];
#pragma unroll
        for (int j = 0; j < 6; j++) { m[j] = -1e30f; den[j] = 0.f; }
        for (int e = start + lane; e < end; e += 64) {
            int s = csr[e];
            f32x4 x0 = *(const f32x4*)(asn + (size_t)s * 8);
            f32x4 x1 = *(const f32x4*)(asn + (size_t)s * 8 + 4);
            float av[6] = {x0[0], x0[1], x0[2], x0[3], x1[0], x1[1]};
#pragma unroll
            for (int j = 0; j < 6; j++) m[j] = fmaxf(m[j], lrelu(av[j] + adh[j]));
        }
#pragma unroll
        for (int off = 32; off; off >>= 1)
#pragma unroll
            for (int j = 0; j < 6; j++) m[j] = fmaxf(m[j], __shfl_xor(m[j], off));
        for (int e = start + lane; e < end; e += 64) {
            int s = csr[e];
            f32x4 x0 = *(const f32x4*)(asn + (size_t)s * 8);
            f32x4 x1 = *(const f32x4*)(asn + (size_t)s * 8 + 4);
            float av[6] = {x0[0], x0[1], x0[2], x0[3], x1[0], x1[1]};
#pragma unroll
            for (int j = 0; j < 6; j++) den[j] += __expf(lrelu(av[j] + adh[j]) - m[j]);
        }
#pragma unroll
        for (int off = 32; off; off >>= 1)
#pragma unroll
            for (int j = 0; j < 6; j++) den[j] += __shfl_xor(den[j], off);
        for (int e = start + lane; e < end; e += 64) {
            int s = csr[e];
            f32x4 x0 = *(const f32x4*)(asn + (size_t)s * 8);
            f32x4 x1 = *(const f32x4*)(asn + (size_t)s * 8 + 4);
            float av[6] = {x0[0], x0[1], x0[2], x0[3], x1[0], x1[1]};
            f16x8 o;
#pragma unroll
            for (int j = 0; j < 6; j++)
                o[j] = (_Float16)(__expf(lrelu(av[j] + adh[j]) - m[j]) / (den[j] + 1e-16f));
            o[6] = (_Float16)0.f;
            o[7] = (_Float16)0.f;
            *(f16x8*)(w2 + (size_t)e * 8) = o;
        }
    }
}

// ---------------- sliced layer-2 aggregation (h2 stride 256, 32-ch slices) ----------------
__global__ __launch_bounds__(256) void agg2s(const _Float16* __restrict__ h2,
                                             const _Float16* __restrict__ w2,
                                             const int* __restrict__ rowptr,
                                             const int* __restrict__ csr,
                                             float* __restrict__ aggF) {
    int bid = blockIdx.x;
    int slice = bid & 7, grp = bid >> 3;
    int wid = threadIdx.x >> 6, lane = threadIdx.x & 63;
    int i = grp * 4 + wid;
    if (i >= NN) return;
    int start = rowptr[i], end = rowptr[i + 1];
    int lq = lane & 7, eq = lane >> 3;
    int ch = slice * 32 + lq * 4;
    int head = ch / 40;  // pad heads 6,7 have w2 == 0
    const char* hb = (const char*)h2 + (size_t)ch * 2;
    f32x4 acc = {0.f, 0.f, 0.f, 0.f}, acc2 = {0.f, 0.f, 0.f, 0.f};
    int e0 = start;
    for (; e0 + 16 <= end; e0 += 16) {
        int e = e0 + eq, e2 = e0 + 8 + eq;
        int s = csr[e], s2 = csr[e2];
        float w = (float)w2[(size_t)e * 8 + head];
        float ww = (float)w2[(size_t)e2 * 8 + head];
        f16x4 p = *(const f16x4*)(hb + (u32)s * 512u);
        f16x4 p2 = *(const f16x4*)(hb + (u32)s2 * 512u);
#pragma unroll
        for (int j = 0; j < 4; j++) {
            acc[j] += w * (float)p[j];
            acc2[j] += ww * (float)p2[j];
        }
    }
    for (; e0 < end; e0 += 8) {
        int e = e0 + eq;
        if (e < end) {
            int s = csr[e];
            float w = (float)w2[(size_t)e * 8 + head];
            f16x4 p = *(const f16x4*)(hb + (u32)s * 512u);
#pragma unroll
            for (int j = 0; j < 4; j++) acc[j] += w * (float)p[j];
        }
    }
#pragma unroll
    for (int j = 0; j < 4; j++) acc[j] += acc2[j];
#pragma unroll
    for (int off = 8; off < 64; off <<= 1)
#pragma unroll
        for (int j = 0; j < 4; j++) acc[j] += __shfl_xor(acc[j], off);
    if (lane < 8 && ch < 240) *(f32x4*)(aggF + (size_t)i * 240 + ch) = acc;
}

// ---------------- final: head-mean + bias + log_softmax ----------------
__global__ void finalk(const float* __restrict__ agg, const float* __restrict__ b2,
                       float* __restrict__ out) {
    int wave = threadIdx.x >> 6, lane = threadIdx.x & 63;
    int i = blockIdx.x * 4 + wave;
    if (i >= NN) return;
    float v = 0.f;
    if (lane < 40) {
#pragma unroll
        for (int hh = 0; hh < 6; hh++) v += agg[(size_t)i * 240 + hh * 40 + lane];
        v = v * (1.0f / 6.0f) + b2[lane];
    }
    float m = lane < 40 ? v : -INFINITY;
#pragma unroll
    for (int off = 32; off; off >>= 1) m = fmaxf(m, __shfl_xor(m, off));
    float s = lane < 40 ? __expf(v - m) : 0.f;
#pragma unroll
    for (int off = 32; off; off >>= 1) s += __shfl_xor(s, off);
    if (lane < 40) out[(size_t)i * 40 + lane] = v - m - logf(s);
}

extern "C" void kernel_launch(void* const* d_in, const int* in_sizes, int n_in,
                              void* d_out, int out_size, void* d_ws, size_t ws_size,
                              hipStream_t stream) {
    const float* x   = (const float*)d_in[0];
    const int*   ei  = (const int*)d_in[1];
    const float* W0  = (const float*)d_in[2];
    const float* as0 = (const float*)d_in[3];
    const float* ad0 = (const float*)d_in[4];
    const float* b0  = (const float*)d_in[5];
    const float* g0  = (const float*)d_in[6];
    const float* bt0 = (const float*)d_in[7];
    const float* m0  = (const float*)d_in[8];
    const float* v0  = (const float*)d_in[9];
    const float* W1  = (const float*)d_in[10];
    const float* as1 = (const float*)d_in[11];
    const float* ad1 = (const float*)d_in[12];
    const float* b1  = (const float*)d_in[13];
    const float* g1  = (const float*)d_in[14];
    const float* bt1 = (const float*)d_in[15];
    const float* m1  = (const float*)d_in[16];
    const float* v1  = (const float*)d_in[17];
    const float* W2  = (const float*)d_in[18];
    const float* as2w = (const float*)d_in[19];
    const float* ad2w = (const float*)d_in[20];
    const float* b2  = (const float*)d_in[21];
    float* out = (float*)d_out;
    const int* srcv = ei;
    const int* dstv = ei + EE;

    char* w = (char*)d_ws;
    auto carve = [&](size_t bytes) {
        char* p = w;
        w += (bytes + 255) & ~(size_t)255;
        return p;
    };
    _Float16* xh   = (_Float16*)carve((size_t)NN * 128 * 2);
    _Float16* hA   = (_Float16*)carve((size_t)NN * 512 * 2);
    _Float16* actB = (_Float16*)carve((size_t)NN * 512 * 2);
    _Float16* W0t  = (_Float16*)carve((size_t)512 * 128 * 2);
    _Float16* W1t  = (_Float16*)carve((size_t)512 * 512 * 2);
    _Float16* W2t  = (_Float16*)carve((size_t)240 * 512 * 2);
    float* asn  = (float*)carve((size_t)NN * 8 * 4);
    float* adn  = (float*)carve((size_t)NN * 8 * 4);
    _Float16* wE = (_Float16*)carve((size_t)EPQ * 8 * 2);  // L01: stride 4; L2: stride 8
    int* count  = (int*)carve((size_t)(NN + 8) * 4);
    int* excl   = (int*)carve((size_t)(NN + 8) * 4);
    int* bsum   = (int*)carve((size_t)512 * 4);
    int* boff   = (int*)carve((size_t)512 * 4);
    int* rowptr = (int*)carve((size_t)(NN + 8) * 4);
    int* cursor = (int*)carve((size_t)(NN + 8) * 4);
    int* csrs   = (int*)carve((size_t)EPQ * 4);
    _Float16* h2p = hA;           // reuse: L2 GEMM output [NN][256] padded
    float* aggF   = (float*)actB; // reuse: [NN][240] f32 (48MB <= 51.2MB)

    // CSR build
    init_count<<<(NN + 255) / 256, 256, 0, stream>>>(count);
    hist_kernel<<<(EE + 255) / 256, 256, 0, stream>>>(dstv, count);
    scan1<<<NBLK, SCB, 0, stream>>>(count, excl, bsum);
    scan2<<<1, 256, 0, stream>>>(bsum, boff);
    scan3<<<(NN + 256) / 256, 256, 0, stream>>>(excl, boff, rowptr, cursor);
    scatter_kernel<<<(EPQ + 255) / 256, 256, 0, stream>>>(srcv, dstv, cursor, csrs);

    // casts
    cast_x_kernel<<<(NN * 128 / 4 + 255) / 256, 256, 0, stream>>>(x, xh, NN * 128 / 4);
    tcast_kernel<<<dim3(16, 4), 256, 0, stream>>>(W0, W0t, 128, 512);
    tcast_kernel<<<dim3(16, 16), 256, 0, stream>>>(W1, W1t, 512, 512);
    tcast_kernel<<<dim3(8, 16), 256, 0, stream>>>(W2, W2t, 512, 240);

    const int MT = (NN + 127) / 128;   // 391
    const int NG = (NN + 3) / 4;       // 12500
    const int SG = 8 * NG;             // sliced grids

    // Layer 0
    gemm_f16<<<dim3(MT, 4), 256, 0, stream>>>(xh, W0t, hA, NN, 512, 128, 512);
    alpha01<<<NG, 256, 0, stream>>>(hA, as0, ad0, asn, adn);
    wsoft01<<<NG, 256, 0, stream>>>(asn, adn, rowptr, csrs, wE);
    agg01s<<<SG, 256, 0, stream>>>(hA, wE, rowptr, csrs, b0, g0, bt0, m0, v0, actB);

    // Layer 1
    gemm_f16<<<dim3(MT, 4), 256, 0, stream>>>(actB, W1t, hA, NN, 512, 512, 512);
    alpha01<<<NG, 256, 0, stream>>>(hA, as1, ad1, asn, adn);
    wsoft01<<<NG, 256, 0, stream>>>(asn, adn, rowptr, csrs, wE);
    agg01s<<<SG, 256, 0, stream>>>(hA, wE, rowptr, csrs, b1, g1, bt1, m1, v1, actB);

    // Layer 2
    gemm_f16<<<dim3(MT, 2), 256, 0, stream>>>(actB, W2t, h2p, NN, 240, 512, 256);
    alpha2k<<<NG, 256, 0, stream>>>(h2p, as2w, ad2w, asn, adn);
    wsoft2<<<NG, 256, 0, stream>>>(asn, adn, rowptr, csrs, wE);
    agg2s<<<SG, 256, 0, stream>>>(h2p, wE, rowptr, csrs, aggF);
    finalk<<<NG, 256, 0, stream>>>(aggF, b2, out);
}

// Round 6
// 698.589 us; speedup vs baseline: 1.5847x; 1.5847x over previous
//
#include <hip/hip_runtime.h>
#include <cstdint>
#include <cstddef>

#define NN 50000
#define EE 800000
#define EPQ (EE + NN)
#define NEG_SLOPE 0.2f
#define BN_EPS 1e-5f
#define SCB 256
#define NBLK ((NN + SCB - 1) / SCB)

typedef _Float16 f16x8 __attribute__((ext_vector_type(8)));
typedef _Float16 f16x4 __attribute__((ext_vector_type(4)));
typedef _Float16 f16x2 __attribute__((ext_vector_type(2)));
typedef float f32x4 __attribute__((ext_vector_type(4)));
typedef float f32x2 __attribute__((ext_vector_type(2)));
typedef unsigned int u32;

static __device__ __forceinline__ float lrelu(float x) { return x > 0.f ? x : x * NEG_SLOPE; }

// async global->LDS, 16B per lane; LDS dest = wave-uniform base + lane*16
static __device__ __forceinline__ void gld_lds16(const void* g, void* l) {
    __builtin_amdgcn_global_load_lds((const __attribute__((address_space(1))) u32*)g,
                                     (__attribute__((address_space(3))) u32*)l, 16, 0, 0);
}

// ---------------- CSR build ----------------
__global__ void init_count(int* __restrict__ count) {
    int i = blockIdx.x * blockDim.x + threadIdx.x;
    if (i < NN) count[i] = 1;  // self loop
}

__global__ void hist_kernel(const int* __restrict__ dst, int* __restrict__ count) {
    int e = blockIdx.x * blockDim.x + threadIdx.x;
    if (e < EE) atomicAdd(&count[dst[e]], 1);
}

__global__ __launch_bounds__(SCB) void scan1(const int* __restrict__ count,
                                             int* __restrict__ excl, int* __restrict__ bsum) {
    __shared__ int tmp[SCB];
    int b = blockIdx.x, t = threadIdx.x;
    int i = b * SCB + t;
    int v = (i < NN) ? count[i] : 0;
    tmp[t] = v;
    __syncthreads();
    for (int off = 1; off < SCB; off <<= 1) {
        int u = (t >= off) ? tmp[t - off] : 0;
        __syncthreads();
        tmp[t] += u;
        __syncthreads();
    }
    if (i < NN) excl[i] = tmp[t] - v;
    if (t == SCB - 1) bsum[b] = tmp[t];
}

__global__ __launch_bounds__(256) void scan2(const int* __restrict__ bsum, int* __restrict__ boff) {
    __shared__ int tmp[256];
    int t = threadIdx.x;
    int v = (t < NBLK) ? bsum[t] : 0;
    tmp[t] = v;
    __syncthreads();
    for (int off = 1; off < 256; off <<= 1) {
        int u = (t >= off) ? tmp[t - off] : 0;
        __syncthreads();
        tmp[t] += u;
        __syncthreads();
    }
    boff[t] = tmp[t] - v;
}

__global__ void scan3(const int* __restrict__ excl, const int* __restrict__ boff,
                      int* __restrict__ rowptr, int* __restrict__ cursor) {
    int i = blockIdx.x * blockDim.x + threadIdx.x;
    if (i < NN) {
        int r = excl[i] + boff[i / SCB];
        rowptr[i] = r;
        cursor[i] = r;
    }
    if (i == NN) rowptr[NN] = EPQ;
}

__global__ void scatter_kernel(const int* __restrict__ src, const int* __restrict__ dst,
                               int* __restrict__ cursor, int* __restrict__ csrs) {
    int e = blockIdx.x * blockDim.x + threadIdx.x;
    if (e < EE) {
        int d = dst[e];
        int slot = atomicAdd(&cursor[d], 1);
        csrs[slot] = src[e];
    } else if (e < EPQ) {
        int i = e - EE;
        int slot = atomicAdd(&cursor[i], 1);
        csrs[slot] = i;
    }
}

// ---------------- casts ----------------
__global__ void cast_x_kernel(const float* __restrict__ in, _Float16* __restrict__ out, int n4) {
    int i = blockIdx.x * blockDim.x + threadIdx.x;
    if (i >= n4) return;
    f32x4 v = *(const f32x4*)(in + (size_t)i * 4);
    f16x4 o;
    o[0] = (_Float16)v[0]; o[1] = (_Float16)v[1]; o[2] = (_Float16)v[2]; o[3] = (_Float16)v[3];
    *(f16x4*)(out + (size_t)i * 4) = o;
}

// W [K][Nc] f32 -> Wt [Nc][K] f16
__global__ __launch_bounds__(256) void tcast_kernel(const float* __restrict__ W,
                                                    _Float16* __restrict__ Wt, int K, int Nc) {
    __shared__ float tile[32][33];
    int bx = blockIdx.x * 32;
    int by = blockIdx.y * 32;
    int tx = threadIdx.x & 31, ty = threadIdx.x >> 5;
#pragma unroll
    for (int r = 0; r < 32; r += 8) {
        int k = by + ty + r, n = bx + tx;
        tile[ty + r][tx] = (k < K && n < Nc) ? W[(size_t)k * Nc + n] : 0.f;
    }
    __syncthreads();
#pragma unroll
    for (int r = 0; r < 32; r += 8) {
        int n = bx + ty + r, k = by + tx;
        if (n < Nc && k < K) Wt[(size_t)n * K + k] = (_Float16)tile[tx][ty + r];
    }
}

// ---------------- prep: BN scale/shift  val = acc*sc + sh ----------------
__global__ void prep_bn(const float* g0, const float* bt0, const float* m0, const float* v0,
                        const float* b0, const float* g1, const float* bt1, const float* m1,
                        const float* v1, const float* b1, float* sc01, float* sh01) {
    int t = threadIdx.x;
    const float *g, *bt, *m, *v, *b;
    int c;
    if (t < 512) { g = g0; bt = bt0; m = m0; v = v0; b = b0; c = t; }
    else         { g = g1; bt = bt1; m = m1; v = v1; b = b1; c = t - 512; }
    float s = g[c] * rsqrtf(v[c] + BN_EPS);
    sc01[t] = s;
    sh01[t] = (b[c] - m[c]) * s + bt[c];
}

// ---------------- prep: projected attention vectors va = W_h @ a_h ----------------
// grid 28 x 512: bid<8 -> va0[8][128]; 8..15 -> va1[8][512]; 16..27 -> va2[12][512]
__global__ __launch_bounds__(512) void prep_va(const _Float16* __restrict__ W0t,
                                               const _Float16* __restrict__ W1t,
                                               const _Float16* __restrict__ W2t,
                                               const float* __restrict__ as0,
                                               const float* __restrict__ ad0,
                                               const float* __restrict__ as1,
                                               const float* __restrict__ ad1,
                                               const float* __restrict__ as2,
                                               const float* __restrict__ ad2,
                                               float* __restrict__ va0, float* __restrict__ va1,
                                               float* __restrict__ va2) {
    int bid = blockIdx.x, t = threadIdx.x;
    if (bid < 8) {
        if (t >= 128) return;
        int j = bid, h = j & 3;
        const float* a = (j < 4 ? as0 : ad0) + h * 128;
        float s = 0.f;
        for (int c = 0; c < 128; c++) s += (float)W0t[(size_t)(h * 128 + c) * 128 + t] * a[c];
        va0[j * 128 + t] = s;
    } else if (bid < 16) {
        int j = bid - 8, h = j & 3;
        const float* a = (j < 4 ? as1 : ad1) + h * 128;
        float s = 0.f;
        for (int c = 0; c < 128; c++) s += (float)W1t[(size_t)(h * 128 + c) * 512 + t] * a[c];
        va1[j * 512 + t] = s;
    } else {
        int j = bid - 16, h = j % 6;
        const float* a = (j < 6 ? as2 : ad2) + h * 40;
        float s = 0.f;
        for (int c = 0; c < 40; c++) s += (float)W2t[(size_t)(h * 40 + c) * 512 + t] * a[c];
        va2[j * 512 + t] = s;
    }
}

// ---------------- f16 MFMA GEMM, dbuf prefetch; BD: block-diagonal A; EPI: BN+ELU ----------
template <bool BD, bool EPI>
__global__ __launch_bounds__(256) void gemm_t(const _Float16* __restrict__ A, int lda,
                                              const _Float16* __restrict__ Bt,
                                              _Float16* __restrict__ C, int ldc, int M, int Nc,
                                              int K, const float* __restrict__ sc,
                                              const float* __restrict__ sh) {
    __shared__ __align__(16) _Float16 As[2][128 * 64];
    __shared__ __align__(16) _Float16 Bs[2][128 * 64];
    const int t = threadIdx.x;
    const int bm = blockIdx.x * 128;
    const int bn = blockIdx.y * 128;
    const int wid = t >> 6, lane = t & 63;
    const int wm = (wid >> 1) * 64, wn = (wid & 1) * 64;
    const int aoff = BD ? bn : 0;
    f32x4 acc[4][4] = {};
    const int nsteps = K >> 6;

    auto STAGE = [&](int buf, int k0) {
#pragma unroll
        for (int it = 0; it < 4; ++it) {
            int rbase = it * 32 + wid * 8;
            int row = rbase + (lane >> 3);
            int c8g = (lane & 7) ^ (row & 7);
            gld_lds16(A + (size_t)(bm + row) * lda + aoff + k0 + c8g * 8,
                      (char*)As[buf] + rbase * 128);
            gld_lds16(Bt + (size_t)(bn + row) * K + k0 + c8g * 8, (char*)Bs[buf] + rbase * 128);
        }
    };

    STAGE(0, 0);
    __syncthreads();
    int cur = 0;
    for (int s = 0; s < nsteps; ++s) {
        if (s + 1 < nsteps) STAGE(cur ^ 1, (s + 1) * 64);
#pragma unroll
        for (int ks = 0; ks < 2; ++ks) {
            f16x8 af[4], bf[4];
#pragma unroll
            for (int mi = 0; mi < 4; ++mi) {
                int row = wm + mi * 16 + (lane & 15);
                int c8 = (ks * 4 + (lane >> 4)) ^ (row & 7);
                af[mi] = *(const f16x8*)((const char*)As[cur] + row * 128 + c8 * 16);
            }
#pragma unroll
            for (int ni = 0; ni < 4; ++ni) {
                int row = wn + ni * 16 + (lane & 15);
                int c8 = (ks * 4 + (lane >> 4)) ^ (row & 7);
                bf[ni] = *(const f16x8*)((const char*)Bs[cur] + row * 128 + c8 * 16);
            }
#pragma unroll
            for (int mi = 0; mi < 4; ++mi)
#pragma unroll
                for (int ni = 0; ni < 4; ++ni)
                    acc[mi][ni] = __builtin_amdgcn_mfma_f32_16x16x32_f16(af[mi], bf[ni],
                                                                         acc[mi][ni], 0, 0, 0);
        }
        __syncthreads();
        cur ^= 1;
    }
    float scv[4], shv[4];
    if (EPI) {
#pragma unroll
        for (int ni = 0; ni < 4; ++ni) {
            int gcol = bn + wn + ni * 16 + (lane & 15);
            scv[ni] = sc[gcol];
            shv[ni] = sh[gcol];
        }
    }
#pragma unroll
    for (int mi = 0; mi < 4; ++mi) {
#pragma unroll
        for (int r = 0; r < 4; ++r) {
            int grow = bm + wm + mi * 16 + (lane >> 4) * 4 + r;
            if (grow < M) {
#pragma unroll
                for (int ni = 0; ni < 4; ++ni) {
                    int gcol = bn + wn + ni * 16 + (lane & 15);
                    if (gcol < Nc) {
                        float v = acc[mi][ni][r];
                        if (EPI) {
                            v = v * scv[ni] + shv[ni];
                            v = v > 0.f ? v : expm1f(v);
                        }
                        C[(size_t)grow * ldc + gcol] = (_Float16)v;
                    }
                }
            }
        }
    }
}

// ---------------- alpha L0: asn/adn[i,h] = x[i] . va0[h] ----------------
__global__ __launch_bounds__(256) void alpha0(const _Float16* __restrict__ xh,
                                              const float* __restrict__ va0,
                                              float* __restrict__ asn, float* __restrict__ adn) {
    int wid = threadIdx.x >> 6, lane = threadIdx.x & 63;
    int i = blockIdx.x * 4 + wid;
    if (i >= NN) return;
    f16x2 x2 = *(const f16x2*)(xh + (size_t)i * 128 + lane * 2);
    float x0 = (float)x2[0], x1 = (float)x2[1];
    float p[8];
#pragma unroll
    for (int j = 0; j < 8; j++) {
        f32x2 v = *(const f32x2*)(va0 + j * 128 + lane * 2);
        p[j] = x0 * v[0] + x1 * v[1];
    }
#pragma unroll
    for (int off = 32; off; off >>= 1)
#pragma unroll
        for (int j = 0; j < 8; j++) p[j] += __shfl_xor(p[j], off);
    if (lane == 0) {
        f32x4 o0 = {p[0], p[1], p[2], p[3]}, o1 = {p[4], p[5], p[6], p[7]};
        *(f32x4*)(asn + (size_t)i * 4) = o0;
        *(f32x4*)(adn + (size_t)i * 4) = o1;
    }
}

// ---------------- alpha L1/L2: asn/adn[i,j] = feat[i](512) . va[j] ----------------
template <int JH, int STR>
__global__ __launch_bounds__(256) void alpha12(const _Float16* __restrict__ feat,
                                               const float* __restrict__ va,
                                               float* __restrict__ asn, float* __restrict__ adn) {
    int wid = threadIdx.x >> 6, lane = threadIdx.x & 63;
    int i = blockIdx.x * 4 + wid;
    if (i >= NN) return;
    f16x8 x8 = *(const f16x8*)(feat + (size_t)i * 512 + lane * 8);
    float xf[8];
#pragma unroll
    for (int u = 0; u < 8; u++) xf[u] = (float)x8[u];
    float p[2 * JH];
#pragma unroll
    for (int j = 0; j < 2 * JH; j++) {
        const float* vr = va + j * 512 + lane * 8;
        f32x4 v0 = *(const f32x4*)vr;
        f32x4 v1 = *(const f32x4*)(vr + 4);
        p[j] = xf[0] * v0[0] + xf[1] * v0[1] + xf[2] * v0[2] + xf[3] * v0[3] +
               xf[4] * v1[0] + xf[5] * v1[1] + xf[6] * v1[2] + xf[7] * v1[3];
    }
#pragma unroll
    for (int off = 32; off; off >>= 1)
#pragma unroll
        for (int j = 0; j < 2 * JH; j++) p[j] += __shfl_xor(p[j], off);
    if (lane == 0) {
#pragma unroll
        for (int h = 0; h < JH; h++) {
            asn[(size_t)i * STR + h] = p[h];
            adn[(size_t)i * STR + h] = p[JH + h];
        }
    }
}

// ---------------- per-edge normalized weights (4 heads, stride-4 f16) ----------------
__global__ __launch_bounds__(256) void wsoft01(const float* __restrict__ asn,
                                               const float* __restrict__ adn,
                                               const int* __restrict__ rowptr,
                                               const int* __restrict__ csr,
                                               _Float16* __restrict__ wA) {
    int wid = threadIdx.x >> 6, lane = threadIdx.x & 63;
    int i = blockIdx.x * 4 + wid;
    if (i >= NN) return;
    int start = rowptr[i], end = rowptr[i + 1], deg = end - start;
    f32x4 ad = *(const f32x4*)(adn + (size_t)i * 4);
    if (deg <= 64) {
        bool v = lane < deg;
        int e = start + (v ? lane : 0);
        int s = csr[e];
        f32x4 a = *(const f32x4*)(asn + (size_t)s * 4);
        f32x4 sc;
#pragma unroll
        for (int j = 0; j < 4; j++) sc[j] = v ? lrelu(a[j] + ad[j]) : -1e30f;
        f32x4 m = sc;
#pragma unroll
        for (int off = 32; off; off >>= 1)
#pragma unroll
            for (int j = 0; j < 4; j++) m[j] = fmaxf(m[j], __shfl_xor(m[j], off));
        f32x4 wv;
#pragma unroll
        for (int j = 0; j < 4; j++) wv[j] = v ? __expf(sc[j] - m[j]) : 0.f;
        f32x4 den = wv;
#pragma unroll
        for (int off = 32; off; off >>= 1)
#pragma unroll
            for (int j = 0; j < 4; j++) den[j] += __shfl_xor(den[j], off);
        if (v) {
            f16x4 o;
#pragma unroll
            for (int j = 0; j < 4; j++) o[j] = (_Float16)(wv[j] / (den[j] + 1e-16f));
            *(f16x4*)(wA + (size_t)e * 4) = o;
        }
    } else {
        f32x4 m = {-1e30f, -1e30f, -1e30f, -1e30f};
        for (int e = start + lane; e < end; e += 64) {
            int s = csr[e];
            f32x4 a = *(const f32x4*)(asn + (size_t)s * 4);
#pragma unroll
            for (int j = 0; j < 4; j++) m[j] = fmaxf(m[j], lrelu(a[j] + ad[j]));
        }
#pragma unroll
        for (int off = 32; off; off >>= 1)
#pragma unroll
            for (int j = 0; j < 4; j++) m[j] = fmaxf(m[j], __shfl_xor(m[j], off));
        f32x4 den = {0.f, 0.f, 0.f, 0.f};
        for (int e = start + lane; e < end; e += 64) {
            int s = csr[e];
            f32x4 a = *(const f32x4*)(asn + (size_t)s * 4);
#pragma unroll
            for (int j = 0; j < 4; j++) den[j] += __expf(lrelu(a[j] + ad[j]) - m[j]);
        }
#pragma unroll
        for (int off = 32; off; off >>= 1)
#pragma unroll
            for (int j = 0; j < 4; j++) den[j] += __shfl_xor(den[j], off);
        for (int e = start + lane; e < end; e += 64) {
            int s = csr[e];
            f32x4 a = *(const f32x4*)(asn + (size_t)s * 4);
            f16x4 o;
#pragma unroll
            for (int j = 0; j < 4; j++)
                o[j] = (_Float16)(__expf(lrelu(a[j] + ad[j]) - m[j]) / (den[j] + 1e-16f));
            *(f16x4*)(wA + (size_t)e * 4) = o;
        }
    }
}

// ---------------- L0: aggregate x-space (128 ch) per head -> xa[NN][4*128] ----------------
__global__ __launch_bounds__(256) void aggx(const _Float16* __restrict__ xh,
                                            const _Float16* __restrict__ wA,
                                            const int* __restrict__ rowptr,
                                            const int* __restrict__ csr,
                                            _Float16* __restrict__ xa) {
    int wid = threadIdx.x >> 6, lane = threadIdx.x & 63;
    int i = blockIdx.x * 4 + wid;
    if (i >= NN) return;
    int start = rowptr[i], end = rowptr[i + 1];
    const char* xb = (const char*)xh + lane * 4;
    float acc0[8] = {}, acc1[8] = {};
    int e = start;
    for (; e + 2 <= end; e += 2) {
        int s0 = csr[e], s1 = csr[e + 1];
        f16x4 w0 = *(const f16x4*)(wA + (size_t)e * 4);
        f16x4 w1 = *(const f16x4*)(wA + (size_t)(e + 1) * 4);
        f16x2 p0 = *(const f16x2*)(xb + (u32)s0 * 256u);
        f16x2 p1 = *(const f16x2*)(xb + (u32)s1 * 256u);
        float q00 = (float)p0[0], q01 = (float)p0[1];
        float q10 = (float)p1[0], q11 = (float)p1[1];
#pragma unroll
        for (int h = 0; h < 4; h++) {
            float wh0 = (float)w0[h], wh1 = (float)w1[h];
            acc0[h * 2] += wh0 * q00;
            acc0[h * 2 + 1] += wh0 * q01;
            acc1[h * 2] += wh1 * q10;
            acc1[h * 2 + 1] += wh1 * q11;
        }
    }
    if (e < end) {
        int s0 = csr[e];
        f16x4 w0 = *(const f16x4*)(wA + (size_t)e * 4);
        f16x2 p0 = *(const f16x2*)(xb + (u32)s0 * 256u);
        float q00 = (float)p0[0], q01 = (float)p0[1];
#pragma unroll
        for (int h = 0; h < 4; h++) {
            float wh0 = (float)w0[h];
            acc0[h * 2] += wh0 * q00;
            acc0[h * 2 + 1] += wh0 * q01;
        }
    }
#pragma unroll
    for (int h = 0; h < 4; h++) {
        f16x2 o;
        o[0] = (_Float16)(acc0[h * 2] + acc1[h * 2]);
        o[1] = (_Float16)(acc0[h * 2 + 1] + acc1[h * 2 + 1]);
        *(f16x2*)(xa + (size_t)i * 512 + h * 128 + lane * 2) = o;
    }
}

// ---------------- L1: gather h1 (512 ch) + BN/ELU epilogue ----------------
__global__ __launch_bounds__(128) void agg01(const _Float16* __restrict__ h,
                                             const _Float16* __restrict__ wA,
                                             const int* __restrict__ rowptr,
                                             const int* __restrict__ csr,
                                             const float* __restrict__ sc,
                                             const float* __restrict__ sh,
                                             _Float16* __restrict__ out) {
    int i = blockIdx.x;
    int t = threadIdx.x;
    int head = t >> 5;
    int ch = t * 4;
    int start = rowptr[i], end = rowptr[i + 1];
    const char* hb = (const char*)h + (size_t)ch * 2;
    f32x4 a0 = {}, a1 = {}, a2 = {}, a3 = {};
    int e = start;
    for (; e + 4 <= end; e += 4) {
        int s0 = csr[e], s1 = csr[e + 1], s2 = csr[e + 2], s3 = csr[e + 3];
        float w0 = (float)wA[(size_t)e * 4 + head];
        float w1 = (float)wA[(size_t)(e + 1) * 4 + head];
        float w2 = (float)wA[(size_t)(e + 2) * 4 + head];
        float w3 = (float)wA[(size_t)(e + 3) * 4 + head];
        f16x4 p0 = *(const f16x4*)(hb + (u32)s0 * 1024u);
        f16x4 p1 = *(const f16x4*)(hb + (u32)s1 * 1024u);
        f16x4 p2 = *(const f16x4*)(hb + (u32)s2 * 1024u);
        f16x4 p3 = *(const f16x4*)(hb + (u32)s3 * 1024u);
#pragma unroll
        for (int j = 0; j < 4; j++) {
            a0[j] += w0 * (float)p0[j];
            a1[j] += w1 * (float)p1[j];
            a2[j] += w2 * (float)p2[j];
            a3[j] += w3 * (float)p3[j];
        }
    }
    for (; e < end; e++) {
        int s0 = csr[e];
        float w0 = (float)wA[(size_t)e * 4 + head];
        f16x4 p0 = *(const f16x4*)(hb + (u32)s0 * 1024u);
#pragma unroll
        for (int j = 0; j < 4; j++) a0[j] += w0 * (float)p0[j];
    }
    f32x4 scv = *(const f32x4*)(sc + ch);
    f32x4 shv = *(const f32x4*)(sh + ch);
    f16x4 o;
#pragma unroll
    for (int j = 0; j < 4; j++) {
        float val = (a0[j] + a1[j] + a2[j] + a3[j]) * scv[j] + shv[j];
        val = val > 0.f ? val : expm1f(val);
        o[j] = (_Float16)val;
    }
    *(f16x4*)(out + (size_t)i * 512 + ch) = o;
}

// ---------------- layer-2 normalized weights (6 heads, stride-8 f16) ----------------
__global__ __launch_bounds__(256) void wsoft2(const float* __restrict__ asn,
                                              const float* __restrict__ adn,
                                              const int* __restrict__ rowptr,
                                              const int* __restrict__ csr,
                                              _Float16* __restrict__ w2) {
    int wid = threadIdx.x >> 6, lane = threadIdx.x & 63;
    int i = blockIdx.x * 4 + wid;
    if (i >= NN) return;
    int start = rowptr[i], end = rowptr[i + 1], deg = end - start;
    f32x4 ad0 = *(const f32x4*)(adn + (size_t)i * 8);
    f32x4 ad1 = *(const f32x4*)(adn + (size_t)i * 8 + 4);
    float adh[6] = {ad0[0], ad0[1], ad0[2], ad0[3], ad1[0], ad1[1]};
    if (deg <= 64) {
        bool v = lane < deg;
        int e = start + (v ? lane : 0);
        int s = csr[e];
        f32x4 x0 = *(const f32x4*)(asn + (size_t)s * 8);
        f32x4 x1 = *(const f32x4*)(asn + (size_t)s * 8 + 4);
        float av[6] = {x0[0], x0[1], x0[2], x0[3], x1[0], x1[1]};
        float sc[6], m[6], wv[6], den[6];
#pragma unroll
        for (int j = 0; j < 6; j++) {
            sc[j] = v ? lrelu(av[j] + adh[j]) : -1e30f;
            m[j] = sc[j];
        }
#pragma unroll
        for (int off = 32; off; off >>= 1)
#pragma unroll
            for (int j = 0; j < 6; j++) m[j] = fmaxf(m[j], __shfl_xor(m[j], off));
#pragma unroll
        for (int j = 0; j < 6; j++) {
            wv[j] = v ? __expf(sc[j] - m[j]) : 0.f;
            den[j] = wv[j];
        }
#pragma unroll
        for (int off = 32; off; off >>= 1)
#pragma unroll
            for (int j = 0; j < 6; j++) den[j] += __shfl_xor(den[j], off);
        if (v) {
            f16x8 o;
#pragma unroll
            for (int j = 0; j < 6; j++) o[j] = (_Float16)(wv[j] / (den[j] + 1e-16f));
            o[6] = (_Float16)0.f;
            o[7] = (_Float16)0.f;
            *(f16x8*)(w2 + (size_t)e * 8) = o;
        }
    } else {
        float m[6], den[6];
#pragma unroll
        for (int j = 0; j < 6; j++) { m[j] = -1e30f; den[j] = 0.f; }
        for (int e = start + lane; e < end; e += 64) {
            int s = csr[e];
            f32x4 x0 = *(const f32x4*)(asn + (size_t)s * 8);
            f32x4 x1 = *(const f32x4*)(asn + (size_t)s * 8 + 4);
            float av[6] = {x0[0], x0[1], x0[2], x0[3], x1[0], x1[1]};
#pragma unroll
            for (int j = 0; j < 6; j++) m[j] = fmaxf(m[j], lrelu(av[j] + adh[j]));
        }
#pragma unroll
        for (int off = 32; off; off >>= 1)
#pragma unroll
            for (int j = 0; j < 6; j++) m[j] = fmaxf(m[j], __shfl_xor(m[j], off));
        for (int e = start + lane; e < end; e += 64) {
            int s = csr[e];
            f32x4 x0 = *(const f32x4*)(asn + (size_t)s * 8);
            f32x4 x1 = *(const f32x4*)(asn + (size_t)s * 8 + 4);
            float av[6] = {x0[0], x0[1], x0[2], x0[3], x1[0], x1[1]};
#pragma unroll
            for (int j = 0; j < 6; j++) den[j] += __expf(lrelu(av[j] + adh[j]) - m[j]);
        }
#pragma unroll
        for (int off = 32; off; off >>= 1)
#pragma unroll
            for (int j = 0; j < 6; j++) den[j] += __shfl_xor(den[j], off);
        for (int e = start + lane; e < end; e += 64) {
            int s = csr[e];
            f32x4 x0 = *(const f32x4*)(asn + (size_t)s * 8);
            f32x4 x1 = *(const f32x4*)(asn + (size_t)s * 8 + 4);
            float av[6] = {x0[0], x0[1], x0[2], x0[3], x1[0], x1[1]};
            f16x8 o;
#pragma unroll
            for (int j = 0; j < 6; j++)
                o[j] = (_Float16)(__expf(lrelu(av[j] + adh[j]) - m[j]) / (den[j] + 1e-16f));
            o[6] = (_Float16)0.f;
            o[7] = (_Float16)0.f;
            *(f16x8*)(w2 + (size_t)e * 8) = o;
        }
    }
}

// ---------------- L2: gather h2 (240 ch, stride 256) + mean + bias + log_softmax ----------
__global__ __launch_bounds__(128) void agg2f(const _Float16* __restrict__ h2,
                                             const _Float16* __restrict__ w2,
                                             const int* __restrict__ rowptr,
                                             const int* __restrict__ csr,
                                             const float* __restrict__ b2,
                                             float* __restrict__ out) {
    __shared__ float sval[240];
    int i = blockIdx.x;
    int t = threadIdx.x;
    int start = rowptr[i], end = rowptr[i + 1];
    if (t < 120) {
        int head = t / 20;
        int ch = t * 2;
        const char* hb = (const char*)h2 + (size_t)ch * 2;
        float a0 = 0.f, a1 = 0.f, b0 = 0.f, b1 = 0.f;
        int e = start;
        for (; e + 2 <= end; e += 2) {
            int s0 = csr[e], s1 = csr[e + 1];
            float w0 = (float)w2[(size_t)e * 8 + head];
            float w1 = (float)w2[(size_t)(e + 1) * 8 + head];
            f16x2 p0 = *(const f16x2*)(hb + (u32)s0 * 512u);
            f16x2 p1 = *(const f16x2*)(hb + (u32)s1 * 512u);
            a0 += w0 * (float)p0[0];
            a1 += w0 * (float)p0[1];
            b0 += w1 * (float)p1[0];
            b1 += w1 * (float)p1[1];
        }
        if (e < end) {
            int s0 = csr[e];
            float w0 = (float)w2[(size_t)e * 8 + head];
            f16x2 p0 = *(const f16x2*)(hb + (u32)s0 * 512u);
            a0 += w0 * (float)p0[0];
            a1 += w0 * (float)p0[1];
        }
        sval[ch] = a0 + b0;
        sval[ch + 1] = a1 + b1;
    }
    __syncthreads();
    if (t < 64) {
        float v = -INFINITY;
        if (t < 40) {
            float s = 0.f;
#pragma unroll
            for (int hh = 0; hh < 6; hh++) s += sval[hh * 40 + t];
            v = s * (1.0f / 6.0f) + b2[t];
        }
        float mm = v;
#pragma unroll
        for (int off = 32; off; off >>= 1) mm = fmaxf(mm, __shfl_xor(mm, off));
        float se = (t < 40) ? __expf(v - mm) : 0.f;
#pragma unroll
        for (int off = 32; off; off >>= 1) se += __shfl_xor(se, off);
        if (t < 40) out[(size_t)i * 40 + t] = v - mm - logf(se);
    }
}

extern "C" void kernel_launch(void* const* d_in, const int* in_sizes, int n_in,
                              void* d_out, int out_size, void* d_ws, size_t ws_size,
                              hipStream_t stream) {
    const float* x   = (const float*)d_in[0];
    const int*   ei  = (const int*)d_in[1];
    const float* W0  = (const float*)d_in[2];
    const float* as0 = (const float*)d_in[3];
    const float* ad0 = (const float*)d_in[4];
    const float* b0  = (const float*)d_in[5];
    const float* g0  = (const float*)d_in[6];
    const float* bt0 = (const float*)d_in[7];
    const float* m0  = (const float*)d_in[8];
    const float* v0  = (const float*)d_in[9];
    const float* W1  = (const float*)d_in[10];
    const float* as1 = (const float*)d_in[11];
    const float* ad1 = (const float*)d_in[12];
    const float* b1  = (const float*)d_in[13];
    const float* g1  = (const float*)d_in[14];
    const float* bt1 = (const float*)d_in[15];
    const float* m1  = (const float*)d_in[16];
    const float* v1  = (const float*)d_in[17];
    const float* W2  = (const float*)d_in[18];
    const float* as2w = (const float*)d_in[19];
    const float* ad2w = (const float*)d_in[20];
    const float* b2  = (const float*)d_in[21];
    float* out = (float*)d_out;
    const int* srcv = ei;
    const int* dstv = ei + EE;

    char* w = (char*)d_ws;
    auto carve = [&](size_t bytes) {
        char* p = w;
        w += (bytes + 255) & ~(size_t)255;
        return p;
    };
    _Float16* xh   = (_Float16*)carve((size_t)NN * 128 * 2);
    _Float16* hA   = (_Float16*)carve((size_t)NN * 512 * 2);   // xa (L0) / h1 (L1) / h2p (L2)
    _Float16* actB = (_Float16*)carve((size_t)NN * 512 * 2);
    _Float16* W0t  = (_Float16*)carve((size_t)512 * 128 * 2);
    _Float16* W1t  = (_Float16*)carve((size_t)512 * 512 * 2);
    _Float16* W2t  = (_Float16*)carve((size_t)240 * 512 * 2);
    float* va0  = (float*)carve((size_t)8 * 128 * 4);
    float* va1  = (float*)carve((size_t)8 * 512 * 4);
    float* va2  = (float*)carve((size_t)12 * 512 * 4);
    float* sc01 = (float*)carve((size_t)1024 * 4);
    float* sh01 = (float*)carve((size_t)1024 * 4);
    float* asn  = (float*)carve((size_t)NN * 8 * 4);
    float* adn  = (float*)carve((size_t)NN * 8 * 4);
    _Float16* wE = (_Float16*)carve((size_t)EPQ * 8 * 2);
    int* count  = (int*)carve((size_t)(NN + 8) * 4);
    int* excl   = (int*)carve((size_t)(NN + 8) * 4);
    int* bsum   = (int*)carve((size_t)512 * 4);
    int* boff   = (int*)carve((size_t)512 * 4);
    int* rowptr = (int*)carve((size_t)(NN + 8) * 4);
    int* cursor = (int*)carve((size_t)(NN + 8) * 4);
    int* csrs   = (int*)carve((size_t)EPQ * 4);
    _Float16* xa  = hA;   // L0 aggregated x-space [NN][4*128]
    _Float16* h2p = hA;   // L2 GEMM output [NN][256] padded

    // CSR build
    init_count<<<(NN + 255) / 256, 256, 0, stream>>>(count);
    hist_kernel<<<(EE + 255) / 256, 256, 0, stream>>>(dstv, count);
    scan1<<<NBLK, SCB, 0, stream>>>(count, excl, bsum);
    scan2<<<1, 256, 0, stream>>>(bsum, boff);
    scan3<<<(NN + 256) / 256, 256, 0, stream>>>(excl, boff, rowptr, cursor);
    scatter_kernel<<<(EPQ + 255) / 256, 256, 0, stream>>>(srcv, dstv, cursor, csrs);

    // casts + prep
    cast_x_kernel<<<(NN * 128 / 4 + 255) / 256, 256, 0, stream>>>(x, xh, NN * 128 / 4);
    tcast_kernel<<<dim3(16, 4), 256, 0, stream>>>(W0, W0t, 128, 512);
    tcast_kernel<<<dim3(16, 16), 256, 0, stream>>>(W1, W1t, 512, 512);
    tcast_kernel<<<dim3(8, 16), 256, 0, stream>>>(W2, W2t, 512, 240);
    prep_bn<<<1, 1024, 0, stream>>>(g0, bt0, m0, v0, b0, g1, bt1, m1, v1, b1, sc01, sh01);
    prep_va<<<28, 512, 0, stream>>>(W0t, W1t, W2t, as0, ad0, as1, ad1, as2w, ad2w, va0, va1, va2);

    const int MT = (NN + 127) / 128;   // 391
    const int NG = (NN + 3) / 4;       // 12500

    // Layer 0: alpha from x, aggregate x-space, block-diagonal GEMM + BN/ELU
    alpha0<<<NG, 256, 0, stream>>>(xh, va0, asn, adn);
    wsoft01<<<NG, 256, 0, stream>>>(asn, adn, rowptr, csrs, wE);
    aggx<<<NG, 256, 0, stream>>>(xh, wE, rowptr, csrs, xa);
    gemm_t<true, true><<<dim3(MT, 4), 256, 0, stream>>>(xa, 512, W0t, actB, 512, NN, 512, 128,
                                                        sc01, sh01);

    // Layer 1: h1 = actB@W1; alpha from actB; gather h1 + BN/ELU
    gemm_t<false, false><<<dim3(MT, 4), 256, 0, stream>>>(actB, 512, W1t, hA, 512, NN, 512, 512,
                                                          nullptr, nullptr);
    alpha12<4, 4><<<NG, 256, 0, stream>>>(actB, va1, asn, adn);
    wsoft01<<<NG, 256, 0, stream>>>(asn, adn, rowptr, csrs, wE);
    agg01<<<NN, 128, 0, stream>>>(hA, wE, rowptr, csrs, sc01 + 512, sh01 + 512, actB);

    // Layer 2: h2 = actB@W2 (padded ldc=256); alpha from actB; gather + final
    gemm_t<false, false><<<dim3(MT, 2), 256, 0, stream>>>(actB, 512, W2t, h2p, 256, NN, 240, 512,
                                                          nullptr, nullptr);
    alpha12<6, 8><<<NG, 256, 0, stream>>>(actB, va2, asn, adn);
    wsoft2<<<NG, 256, 0, stream>>>(asn, adn, rowptr, csrs, wE);
    agg2f<<<NN, 128, 0, stream>>>(h2p, wE, rowptr, csrs, b2, out);
}